// Round 4
// baseline (508.430 us; speedup 1.0000x reference)
//
#include <hip/hip_runtime.h>

#define NN 50000
#define NE 800000

typedef __attribute__((ext_vector_type(8))) short bf16x8;
typedef __attribute__((ext_vector_type(8))) unsigned short us8;
typedef __attribute__((ext_vector_type(4))) unsigned short us4;
typedef __attribute__((ext_vector_type(4))) float f32x4;

#define MFMA16 __builtin_amdgcn_mfma_f32_16x16x32_bf16

__device__ __forceinline__ unsigned short f2b(float f) {
    union { float f; unsigned int u; } x; x.f = f;
    unsigned int r = x.u + 0x7FFFu + ((x.u >> 16) & 1u);
    return (unsigned short)(r >> 16);
}

// packed bf16x2 atomic add (gfx950 native, memory-side RMW, fire-and-forget)
__device__ __forceinline__ void atomic_pk_add_bf16(unsigned short* addr, unsigned int pk) {
    asm volatile("global_atomic_pk_add_bf16 %0, %1, off" :: "v"(addr), "v"(pk) : "memory");
}

// ---------------- prep: convert nodes to bf16; convert+transpose weights ----------------
__global__ __launch_bounds__(256) void prep_kernel(
    const float* __restrict__ nodes,
    const float* __restrict__ We1, const float* __restrict__ We2,
    const float* __restrict__ Wn1, const float* __restrict__ Wn2,
    unsigned short* __restrict__ nodes_bf,
    unsigned short* __restrict__ We1T, unsigned short* __restrict__ We2T,
    unsigned short* __restrict__ Wn1T, unsigned short* __restrict__ Wn2T)
{
    const int b = blockIdx.x, t = threadIdx.x;
    if (b < 400) {
        const float4* src = (const float4*)nodes;
        for (int i = b * 256 + t; i < NN * 16; i += 400 * 256) {
            float4 v = src[i];
            us4 o; o[0] = f2b(v.x); o[1] = f2b(v.y); o[2] = f2b(v.z); o[3] = f2b(v.w);
            *(us4*)&nodes_bf[(size_t)i * 4] = o;
        }
    } else {
        const int base = (b - 400) * 256 + t;
        for (int idx = base; idx < 57344; idx += 16 * 256) {
            if (idx < 24576) {               // We1T[128][192] <- We1[192][128]
                int n = idx / 192, k = idx % 192;
                We1T[idx] = f2b(We1[k * 128 + n]);
            } else if (idx < 32768) {        // We2T[64][128] <- We2[128][64]
                int j = idx - 24576; int n = j / 128, k = j % 128;
                We2T[j] = f2b(We2[k * 64 + n]);
            } else if (idx < 49152) {        // Wn1T[128][128] <- Wn1[128][128]
                int j = idx - 32768; int n = j / 128, k = j % 128;
                Wn1T[j] = f2b(Wn1[k * 128 + n]);
            } else {                         // Wn2T[64][128] <- Wn2[128][64]
                int j = idx - 49152; int n = j / 128, k = j % 128;
                Wn2T[j] = f2b(Wn2[k * 64 + n]);
            }
        }
    }
}

// ---------------- edge kernel: 64 seq edges/block, reg weights, 6 blocks/CU ----------------
// LDS: xs[64][200] bf16 input (hs aliases stride 136; fs aliases f32 stride 68) = 25.6 KB
// + ridx/sidx = 26.1 KB -> 6 blocks/CU.
__global__ __launch_bounds__(256, 6) void edge_kernel(
    const unsigned short* __restrict__ nodes_bf, const float* __restrict__ edges,
    const unsigned short* __restrict__ We1T, const float* __restrict__ be1,
    const unsigned short* __restrict__ We2T, const float* __restrict__ be2,
    const int* __restrict__ senders, const int* __restrict__ receivers,
    unsigned short* __restrict__ agg_bf)
{
    __shared__ __align__(16) unsigned short xs[64 * 200];
    __shared__ int ridx[64];
    __shared__ int sidx[64];

    const int t = threadIdx.x;
    const int e0 = blockIdx.x * 64;
    const int w = t >> 6, l = t & 63, lc = l & 15, lq = l >> 4;

    if (t < 64) {
        ridx[t] = receivers[e0 + t];
        sidx[t] = senders[e0 + t];
    }

    // weights to registers (L2-hot after first wave of blocks): 16 frags
    bf16x8 wA0[6], wA1[6], wB[4];
    #pragma unroll
    for (int c = 0; c < 6; ++c) {
        wA0[c] = *(const bf16x8*)&We1T[(w * 32 + lc) * 192 + c * 32 + lq * 8];
        wA1[c] = *(const bf16x8*)&We1T[(w * 32 + 16 + lc) * 192 + c * 32 + lq * 8];
    }
    #pragma unroll
    for (int c = 0; c < 4; ++c)
        wB[c] = *(const bf16x8*)&We2T[(w * 16 + lc) * 128 + c * 32 + lq * 8];
    const float b1x = be1[w * 32 + lc];
    const float b1y = be1[w * 32 + 16 + lc];
    const float bias2 = be2[w * 16 + lc];

    __syncthreads();   // ridx/sidx visible

    // stage edges (fp32 -> bf16), sequential = coalesced streaming
    #pragma unroll
    for (int i = 0; i < 4; ++i) {
        int idx = t + 256 * i;
        int m = idx >> 4, q = idx & 15;
        float4 v = *(const float4*)&edges[((size_t)(e0 + m)) * 64 + q * 4];
        us4 o; o[0] = f2b(v.x); o[1] = f2b(v.y); o[2] = f2b(v.z); o[3] = f2b(v.w);
        *(us4*)&xs[m * 200 + q * 4] = o;
    }
    // gather receiver node feats
    #pragma unroll
    for (int i = 0; i < 2; ++i) {
        int idx = t + 256 * i;
        int m = idx >> 3, q = idx & 7;
        us8 v = *(const us8*)&nodes_bf[(size_t)ridx[m] * 64 + q * 8];
        *(us8*)&xs[m * 200 + 64 + q * 8] = v;
    }
    // gather sender node feats
    #pragma unroll
    for (int i = 0; i < 2; ++i) {
        int idx = t + 256 * i;
        int m = idx >> 3, q = idx & 7;
        us8 v = *(const us8*)&nodes_bf[(size_t)sidx[m] * 64 + q * 8];
        *(us8*)&xs[m * 200 + 128 + q * 8] = v;
    }
    __syncthreads();

    // GEMM1: [64,192] @ We1[192,128], register weights, no inner barriers
    f32x4 acc[4][2];
    #pragma unroll
    for (int mt = 0; mt < 4; ++mt) { acc[mt][0] = (f32x4)0.f; acc[mt][1] = (f32x4)0.f; }
    #pragma unroll
    for (int c = 0; c < 6; ++c) {
        #pragma unroll
        for (int mt = 0; mt < 4; ++mt) {
            bf16x8 a = *(const bf16x8*)&xs[(mt * 16 + lc) * 200 + c * 32 + lq * 8];
            acc[mt][0] = MFMA16(a, wA0[c], acc[mt][0], 0, 0, 0);
            acc[mt][1] = MFMA16(a, wA1[c], acc[mt][1], 0, 0, 0);
        }
    }
    __syncthreads();

    // bias + relu -> hs (aliases xs, stride 136)
    #pragma unroll
    for (int nt = 0; nt < 2; ++nt) {
        int col = w * 32 + nt * 16 + lc;
        float bias = nt ? b1y : b1x;
        #pragma unroll
        for (int mt = 0; mt < 4; ++mt) {
            #pragma unroll
            for (int r = 0; r < 4; ++r) {
                int row = mt * 16 + lq * 4 + r;
                float v = fmaxf(acc[mt][nt][r] + bias, 0.f);
                xs[row * 136 + col] = f2b(v);
            }
        }
    }
    __syncthreads();

    // GEMM2: [64,128] @ We2[128,64], register weights
    f32x4 acc2[4];
    #pragma unroll
    for (int mt = 0; mt < 4; ++mt) acc2[mt] = (f32x4)0.f;
    #pragma unroll
    for (int c = 0; c < 4; ++c) {
        #pragma unroll
        for (int mt = 0; mt < 4; ++mt) {
            bf16x8 a = *(const bf16x8*)&xs[(mt * 16 + lc) * 136 + c * 32 + lq * 8];
            acc2[mt] = MFMA16(a, wB[c], acc2[mt], 0, 0, 0);
        }
    }
    __syncthreads();   // xs reads done before fs overwrite

    // stage acc2+bias into LDS f32 [64][68] (16B-aligned rows)
    float* fs = (float*)xs;            // 64*68*4 = 17408 B, fits
    {
        const int col = w * 16 + lc;
        #pragma unroll
        for (int mt = 0; mt < 4; ++mt) {
            #pragma unroll
            for (int r = 0; r < 4; ++r) {
                int row = mt * 16 + lq * 4 + r;
                fs[row * 68 + col] = acc2[mt][r] + bias2;
            }
        }
    }
    __syncthreads();

    // packed bf16x2 scatter-add: 2048 pairs, 8 per thread.
    // 32 consecutive lanes cover one agg row's 128B line -> good line locality.
    #pragma unroll
    for (int i = 0; i < 8; ++i) {
        int p = t + 256 * i;
        int row = p >> 5, cp = p & 31;
        float2 v = *(const float2*)&fs[row * 68 + cp * 2];
        unsigned int pk = (unsigned int)f2b(v.x) | ((unsigned int)f2b(v.y) << 16);
        atomic_pk_add_bf16(&agg_bf[(size_t)ridx[row] * 64 + cp * 2], pk);
    }
}

// ---------------- node kernel: 64 nodes/block, reg weights ----------------
__global__ __launch_bounds__(256, 6) void node_kernel(
    const unsigned short* __restrict__ nodes_bf, const unsigned short* __restrict__ agg_bf,
    const unsigned short* __restrict__ Wn1T, const float* __restrict__ bn1,
    const unsigned short* __restrict__ Wn2T, const float* __restrict__ bn2,
    float* __restrict__ out)
{
    __shared__ __align__(16) unsigned short xs[64 * 136];

    const int t = threadIdx.x;
    const int n0 = blockIdx.x * 64;
    const int w = t >> 6, l = t & 63, lc = l & 15, lq = l >> 4;

    // weights to registers: 12 frags
    bf16x8 wA0[4], wA1[4], wB[4];
    #pragma unroll
    for (int c = 0; c < 4; ++c) {
        wA0[c] = *(const bf16x8*)&Wn1T[(w * 32 + lc) * 128 + c * 32 + lq * 8];
        wA1[c] = *(const bf16x8*)&Wn1T[(w * 32 + 16 + lc) * 128 + c * 32 + lq * 8];
        wB[c]  = *(const bf16x8*)&Wn2T[(w * 16 + lc) * 128 + c * 32 + lq * 8];
    }
    const float b1x = bn1[w * 32 + lc];
    const float b1y = bn1[w * 32 + 16 + lc];
    const float bias2 = bn2[w * 16 + lc];

    // stage agg (bf16 copy), cols 0..63
    #pragma unroll
    for (int i = 0; i < 2; ++i) {
        int idx = t + 256 * i;
        int m = idx >> 3, q = idx & 7;
        int n = n0 + m;
        us8 v = {0, 0, 0, 0, 0, 0, 0, 0};
        if (n < NN) v = *(const us8*)&agg_bf[(size_t)n * 64 + q * 8];
        *(us8*)&xs[m * 136 + q * 8] = v;
    }
    // stage node feats (bf16), cols 64..127
    #pragma unroll
    for (int i = 0; i < 2; ++i) {
        int idx = t + 256 * i;
        int m = idx >> 3, q = idx & 7;
        int n = n0 + m;
        us8 v = {0, 0, 0, 0, 0, 0, 0, 0};
        if (n < NN) v = *(const us8*)&nodes_bf[(size_t)n * 64 + q * 8];
        *(us8*)&xs[m * 136 + 64 + q * 8] = v;
    }
    __syncthreads();

    // GEMM1: [64,128] @ Wn1[128,128], register weights
    f32x4 acc[4][2];
    #pragma unroll
    for (int mt = 0; mt < 4; ++mt) { acc[mt][0] = (f32x4)0.f; acc[mt][1] = (f32x4)0.f; }
    #pragma unroll
    for (int c = 0; c < 4; ++c) {
        #pragma unroll
        for (int mt = 0; mt < 4; ++mt) {
            bf16x8 a = *(const bf16x8*)&xs[(mt * 16 + lc) * 136 + c * 32 + lq * 8];
            acc[mt][0] = MFMA16(a, wA0[c], acc[mt][0], 0, 0, 0);
            acc[mt][1] = MFMA16(a, wA1[c], acc[mt][1], 0, 0, 0);
        }
    }
    __syncthreads();

    // bias + relu -> hs (same region, stride 136)
    #pragma unroll
    for (int nt = 0; nt < 2; ++nt) {
        int col = w * 32 + nt * 16 + lc;
        float bias = nt ? b1y : b1x;
        #pragma unroll
        for (int mt = 0; mt < 4; ++mt) {
            #pragma unroll
            for (int r = 0; r < 4; ++r) {
                int row = mt * 16 + lq * 4 + r;
                float v = fmaxf(acc[mt][nt][r] + bias, 0.f);
                xs[row * 136 + col] = f2b(v);
            }
        }
    }
    __syncthreads();

    // GEMM2: [64,128] @ Wn2[128,64], register weights
    f32x4 acc2[4];
    #pragma unroll
    for (int mt = 0; mt < 4; ++mt) acc2[mt] = (f32x4)0.f;
    #pragma unroll
    for (int c = 0; c < 4; ++c) {
        #pragma unroll
        for (int mt = 0; mt < 4; ++mt) {
            bf16x8 a = *(const bf16x8*)&xs[(mt * 16 + lc) * 136 + c * 32 + lq * 8];
            acc2[mt] = MFMA16(a, wB[c], acc2[mt], 0, 0, 0);
        }
    }

    const int col = w * 16 + lc;
    #pragma unroll
    for (int mt = 0; mt < 4; ++mt) {
        #pragma unroll
        for (int r = 0; r < 4; ++r) {
            int row = mt * 16 + lq * 4 + r;
            int n = n0 + row;
            if (n < NN) out[(size_t)n * 64 + col] = acc2[mt][r] + bias2;
        }
    }
}

extern "C" void kernel_launch(void* const* d_in, const int* in_sizes, int n_in,
                              void* d_out, int out_size, void* d_ws, size_t ws_size,
                              hipStream_t stream) {
    const float* nodes = (const float*)d_in[0];
    const float* edges = (const float*)d_in[1];
    const float* We1   = (const float*)d_in[2];
    const float* be1   = (const float*)d_in[3];
    const float* We2   = (const float*)d_in[4];
    const float* be2   = (const float*)d_in[5];
    const float* Wn1   = (const float*)d_in[6];
    const float* bn1   = (const float*)d_in[7];
    const float* Wn2   = (const float*)d_in[8];
    const float* bn2   = (const float*)d_in[9];
    const int* senders   = (const int*)d_in[10];
    const int* receivers = (const int*)d_in[11];
    float* out = (float*)d_out;

    // ws layout (bytes) — proven 19.3 MB layout
    char* ws = (char*)d_ws;
    unsigned short* agg_bf = (unsigned short*)ws;                //  6,400,000 B
    unsigned short* nodes_bf = (unsigned short*)(ws + 12800000); //  6,400,000 B
    unsigned short* We1T = (unsigned short*)(ws + 19200000);     //     49,152 B
    unsigned short* We2T = (unsigned short*)(ws + 19249152);     //     16,384 B
    unsigned short* Wn1T = (unsigned short*)(ws + 19265536);     //     32,768 B
    unsigned short* Wn2T = (unsigned short*)(ws + 19298304);     //     16,384 B

    hipMemsetAsync(agg_bf, 0, (size_t)NN * 64 * sizeof(unsigned short), stream);
    prep_kernel<<<416, 256, 0, stream>>>(nodes, We1, We2, Wn1, Wn2,
                                         nodes_bf, We1T, We2T, Wn1T, Wn2T);
    edge_kernel<<<NE / 64, 256, 0, stream>>>(nodes_bf, edges, We1T, be1, We2T, be2,
                                             senders, receivers, agg_bf);
    node_kernel<<<(NN + 63) / 64, 256, 0, stream>>>(nodes_bf, agg_bf, Wn1T, bn1, Wn2T, bn2, out);
}

// Round 5
// 494.655 us; speedup vs baseline: 1.0278x; 1.0278x over previous
//
#include <hip/hip_runtime.h>

#define NN 50000
#define NE 800000
#define NNP 50176            // 196*256, padded node count for scan
#define SCANB 196

typedef __attribute__((ext_vector_type(8))) short bf16x8;
typedef __attribute__((ext_vector_type(8))) unsigned short us8;
typedef __attribute__((ext_vector_type(4))) unsigned short us4;
typedef __attribute__((ext_vector_type(4))) float f32x4;

#define MFMA16 __builtin_amdgcn_mfma_f32_16x16x32_bf16

__device__ __forceinline__ unsigned short f2b(float f) {
    union { float f; unsigned int u; } x; x.f = f;
    unsigned int r = x.u + 0x7FFFu + ((x.u >> 16) & 1u);
    return (unsigned short)(r >> 16);
}

// packed bf16x2 atomic add (gfx950 native, memory-side RMW, fire-and-forget)
__device__ __forceinline__ void atomic_pk_add_bf16(unsigned short* addr, unsigned int pk) {
    asm volatile("global_atomic_pk_add_bf16 %0, %1, off" :: "v"(addr), "v"(pk) : "memory");
}

// ---------------- prep: convert nodes to bf16; convert+transpose weights ----------------
__global__ __launch_bounds__(256) void prep_kernel(
    const float* __restrict__ nodes,
    const float* __restrict__ We1, const float* __restrict__ We2,
    const float* __restrict__ Wn1, const float* __restrict__ Wn2,
    unsigned short* __restrict__ nodes_bf,
    unsigned short* __restrict__ We1T, unsigned short* __restrict__ We2T,
    unsigned short* __restrict__ Wn1T, unsigned short* __restrict__ Wn2T)
{
    const int b = blockIdx.x, t = threadIdx.x;
    if (b < 400) {
        const float4* src = (const float4*)nodes;
        for (int i = b * 256 + t; i < NN * 16; i += 400 * 256) {
            float4 v = src[i];
            us4 o; o[0] = f2b(v.x); o[1] = f2b(v.y); o[2] = f2b(v.z); o[3] = f2b(v.w);
            *(us4*)&nodes_bf[(size_t)i * 4] = o;
        }
    } else {
        const int base = (b - 400) * 256 + t;
        for (int idx = base; idx < 57344; idx += 16 * 256) {
            if (idx < 24576) {               // We1T[128][192] <- We1[192][128]
                int n = idx / 192, k = idx % 192;
                We1T[idx] = f2b(We1[k * 128 + n]);
            } else if (idx < 32768) {        // We2T[64][128] <- We2[128][64]
                int j = idx - 24576; int n = j / 128, k = j % 128;
                We2T[j] = f2b(We2[k * 64 + n]);
            } else if (idx < 49152) {        // Wn1T[128][128] <- Wn1[128][128]
                int j = idx - 32768; int n = j / 128, k = j % 128;
                Wn1T[j] = f2b(Wn1[k * 128 + n]);
            } else {                         // Wn2T[64][128] <- Wn2[128][64]
                int j = idx - 49152; int n = j / 128, k = j % 128;
                Wn2T[j] = f2b(Wn2[k * 64 + n]);
            }
        }
    }
}

// ---------------- CSR build: histogram + 3-kernel exclusive scan + perm build ----------------
__global__ __launch_bounds__(256) void hist_kernel(
    const int* __restrict__ receivers, int* __restrict__ deg)
{
    int e = blockIdx.x * 256 + threadIdx.x;
    if (e < NE) atomicAdd(&deg[receivers[e]], 1);
}

__global__ __launch_bounds__(256) void scan1_kernel(
    const int* __restrict__ deg, int* __restrict__ psum)
{
    __shared__ int red[256];
    int t = threadIdx.x;
    red[t] = deg[blockIdx.x * 256 + t];
    __syncthreads();
    for (int s = 128; s > 0; s >>= 1) {
        if (t < s) red[t] += red[t + s];
        __syncthreads();
    }
    if (t == 0) psum[blockIdx.x] = red[0];
}

__global__ __launch_bounds__(256) void scan2_kernel(
    const int* __restrict__ psum, int* __restrict__ poff)
{
    __shared__ int a[256];
    int t = threadIdx.x;
    int v0 = (t < SCANB) ? psum[t] : 0;
    a[t] = v0;
    __syncthreads();
    for (int off = 1; off < 256; off <<= 1) {
        int x = a[t];
        if (t >= off) x += a[t - off];
        __syncthreads();
        a[t] = x;
        __syncthreads();
    }
    poff[t] = a[t] - v0;   // exclusive
}

__global__ __launch_bounds__(256) void scan3_kernel(
    const int* __restrict__ deg, const int* __restrict__ poff, int* __restrict__ basep)
{
    __shared__ int a[256];
    int t = threadIdx.x, i = blockIdx.x * 256 + t;
    int v0 = deg[i];
    a[t] = v0;
    __syncthreads();
    for (int off = 1; off < 256; off <<= 1) {
        int x = a[t];
        if (t >= off) x += a[t - off];
        __syncthreads();
        a[t] = x;
        __syncthreads();
    }
    basep[i] = poff[blockIdx.x] + a[t] - v0;   // global exclusive scan
}

__global__ __launch_bounds__(256) void perm_kernel(
    const int* __restrict__ receivers, const int* __restrict__ senders,
    const int* __restrict__ basep, int* __restrict__ cursor,
    int* __restrict__ perm, int* __restrict__ rsorted, int* __restrict__ ssorted)
{
    int e = blockIdx.x * 256 + threadIdx.x;
    if (e < NE) {
        int r = receivers[e];
        int pos = basep[r] + atomicAdd(&cursor[r], 1);
        perm[pos] = e;
        rsorted[pos] = r;
        ssorted[pos] = senders[e];
    }
}

// ---------------- edge kernel: 64 sorted edges/block, reg weights, run-aggregated output ----
// xs[64][200] bf16 input (hs aliases stride 136; fs aliases f32 stride 68) = 25.6 KB
__global__ __launch_bounds__(256, 4) void edge_kernel(
    const unsigned short* __restrict__ nodes_bf, const float* __restrict__ edges,
    const unsigned short* __restrict__ We1T, const float* __restrict__ be1,
    const unsigned short* __restrict__ We2T, const float* __restrict__ be2,
    const int* __restrict__ perm, const int* __restrict__ rsorted,
    const int* __restrict__ ssorted, const int* __restrict__ basep,
    unsigned short* __restrict__ agg_bf)
{
    __shared__ __align__(16) unsigned short xs[64 * 200];
    __shared__ int eidx[64];
    __shared__ int ridx[64];
    __shared__ int sidx[64];
    __shared__ int runStart[65];
    __shared__ int runRecv[64];
    __shared__ int runFull[64];
    __shared__ int nrunsS;

    const int t = threadIdx.x;
    const int e0 = blockIdx.x * 64;
    const int w = t >> 6, l = t & 63, lc = l & 15, lq = l >> 4;

    if (t < 64) {
        eidx[t] = perm[e0 + t];
        ridx[t] = rsorted[e0 + t];    // non-decreasing within block
        sidx[t] = ssorted[e0 + t];
    }

    // weights to registers (L2-hot after first wave of blocks): 16 frags
    bf16x8 wA0[6], wA1[6], wB[4];
    #pragma unroll
    for (int c = 0; c < 6; ++c) {
        wA0[c] = *(const bf16x8*)&We1T[(w * 32 + lc) * 192 + c * 32 + lq * 8];
        wA1[c] = *(const bf16x8*)&We1T[(w * 32 + 16 + lc) * 192 + c * 32 + lq * 8];
    }
    #pragma unroll
    for (int c = 0; c < 4; ++c)
        wB[c] = *(const bf16x8*)&We2T[(w * 16 + lc) * 128 + c * 32 + lq * 8];
    const float b1x = be1[w * 32 + lc];
    const float b1y = be1[w * 32 + 16 + lc];
    const float bias2 = be2[w * 16 + lc];

    __syncthreads();   // eidx/ridx/sidx visible

    // ---- run detection (wave 0 only; threads 0..63 are exactly wave 0) ----
    if (t < 64) {
        int n = ridx[t];
        bool flag = (t == 0) || (n != ridx[t - 1]);
        unsigned long long mask = __ballot(flag);
        int nr = __popcll(mask);
        if (t == 0) { nrunsS = nr; runStart[nr] = 64; }
        if (flag) {
            int rank = __popcll(mask & ((1ULL << t) - 1ULL));
            runStart[rank] = t;
            runRecv[rank] = n;
            // complete iff node's whole CSR range is inside this block
            int s = basep[n], e = basep[n + 1];
            runFull[rank] = (s >= e0) && (e <= e0 + 64);
        }
    }

    // stage edges (fp32 -> bf16), gathered 256B rows (16 threads cover one row)
    #pragma unroll
    for (int i = 0; i < 4; ++i) {
        int idx = t + 256 * i;
        int m = idx >> 4, q = idx & 15;
        float4 v = *(const float4*)&edges[(size_t)eidx[m] * 64 + q * 4];
        us4 o; o[0] = f2b(v.x); o[1] = f2b(v.y); o[2] = f2b(v.z); o[3] = f2b(v.w);
        *(us4*)&xs[m * 200 + q * 4] = o;
    }
    // gather receiver node feats (~5 distinct rows/block -> L1/L2-hot)
    #pragma unroll
    for (int i = 0; i < 2; ++i) {
        int idx = t + 256 * i;
        int m = idx >> 3, q = idx & 7;
        us8 v = *(const us8*)&nodes_bf[(size_t)ridx[m] * 64 + q * 8];
        *(us8*)&xs[m * 200 + 64 + q * 8] = v;
    }
    // gather sender node feats
    #pragma unroll
    for (int i = 0; i < 2; ++i) {
        int idx = t + 256 * i;
        int m = idx >> 3, q = idx & 7;
        us8 v = *(const us8*)&nodes_bf[(size_t)sidx[m] * 64 + q * 8];
        *(us8*)&xs[m * 200 + 128 + q * 8] = v;
    }
    __syncthreads();

    // GEMM1: [64,192] @ We1[192,128], register weights, no inner barriers
    f32x4 acc[4][2];
    #pragma unroll
    for (int mt = 0; mt < 4; ++mt) { acc[mt][0] = (f32x4)0.f; acc[mt][1] = (f32x4)0.f; }
    #pragma unroll
    for (int c = 0; c < 6; ++c) {
        #pragma unroll
        for (int mt = 0; mt < 4; ++mt) {
            bf16x8 a = *(const bf16x8*)&xs[(mt * 16 + lc) * 200 + c * 32 + lq * 8];
            acc[mt][0] = MFMA16(a, wA0[c], acc[mt][0], 0, 0, 0);
            acc[mt][1] = MFMA16(a, wA1[c], acc[mt][1], 0, 0, 0);
        }
    }
    __syncthreads();

    // bias + relu -> hs (aliases xs, stride 136)
    #pragma unroll
    for (int nt = 0; nt < 2; ++nt) {
        int col = w * 32 + nt * 16 + lc;
        float bias = nt ? b1y : b1x;
        #pragma unroll
        for (int mt = 0; mt < 4; ++mt) {
            #pragma unroll
            for (int r = 0; r < 4; ++r) {
                int row = mt * 16 + lq * 4 + r;
                float v = fmaxf(acc[mt][nt][r] + bias, 0.f);
                xs[row * 136 + col] = f2b(v);
            }
        }
    }
    __syncthreads();

    // GEMM2: [64,128] @ We2[128,64], register weights
    f32x4 acc2[4];
    #pragma unroll
    for (int mt = 0; mt < 4; ++mt) acc2[mt] = (f32x4)0.f;
    #pragma unroll
    for (int c = 0; c < 4; ++c) {
        #pragma unroll
        for (int mt = 0; mt < 4; ++mt) {
            bf16x8 a = *(const bf16x8*)&xs[(mt * 16 + lc) * 136 + c * 32 + lq * 8];
            acc2[mt] = MFMA16(a, wB[c], acc2[mt], 0, 0, 0);
        }
    }
    __syncthreads();   // xs reads done before fs overwrite

    // stage acc2+bias2 into LDS f32 [64][68]
    float* fs = (float*)xs;            // 64*68*4 = 17408 B, fits
    {
        const int col = w * 16 + lc;
        #pragma unroll
        for (int mt = 0; mt < 4; ++mt) {
            #pragma unroll
            for (int r = 0; r < 4; ++r) {
                int row = mt * 16 + lq * 4 + r;
                fs[row * 68 + col] = acc2[mt][r] + bias2;
            }
        }
    }
    __syncthreads();

    // ---- run-aggregated output: f32 sum per (run, colpair); store if sole writer ----
    const int nr = nrunsS;
    const int cp = t & 31;
    for (int ri = t >> 5; ri < nr; ri += 8) {
        int rs = runStart[ri], re = runStart[ri + 1];
        float s0 = 0.f, s1 = 0.f;
        for (int r = rs; r < re; ++r) {
            float2 v = *(const float2*)&fs[r * 68 + cp * 2];
            s0 += v.x; s1 += v.y;
        }
        unsigned int pk = (unsigned int)f2b(s0) | ((unsigned int)f2b(s1) << 16);
        unsigned short* addr = &agg_bf[(size_t)runRecv[ri] * 64 + cp * 2];
        if (runFull[ri]) *(unsigned int*)addr = pk;      // complete run: plain store
        else             atomic_pk_add_bf16(addr, pk);   // boundary run: atomic
    }
}

// ---------------- node kernel: 64 nodes/block, reg weights ----------------
__global__ __launch_bounds__(256, 4) void node_kernel(
    const unsigned short* __restrict__ nodes_bf, const unsigned short* __restrict__ agg_bf,
    const unsigned short* __restrict__ Wn1T, const float* __restrict__ bn1,
    const unsigned short* __restrict__ Wn2T, const float* __restrict__ bn2,
    float* __restrict__ out)
{
    __shared__ __align__(16) unsigned short xs[64 * 136];

    const int t = threadIdx.x;
    const int n0 = blockIdx.x * 64;
    const int w = t >> 6, l = t & 63, lc = l & 15, lq = l >> 4;

    // weights to registers: 12 frags
    bf16x8 wA0[4], wA1[4], wB[4];
    #pragma unroll
    for (int c = 0; c < 4; ++c) {
        wA0[c] = *(const bf16x8*)&Wn1T[(w * 32 + lc) * 128 + c * 32 + lq * 8];
        wA1[c] = *(const bf16x8*)&Wn1T[(w * 32 + 16 + lc) * 128 + c * 32 + lq * 8];
        wB[c]  = *(const bf16x8*)&Wn2T[(w * 16 + lc) * 128 + c * 32 + lq * 8];
    }
    const float b1x = bn1[w * 32 + lc];
    const float b1y = bn1[w * 32 + 16 + lc];
    const float bias2 = bn2[w * 16 + lc];

    // stage agg (bf16 copy), cols 0..63
    #pragma unroll
    for (int i = 0; i < 2; ++i) {
        int idx = t + 256 * i;
        int m = idx >> 3, q = idx & 7;
        int n = n0 + m;
        us8 v = {0, 0, 0, 0, 0, 0, 0, 0};
        if (n < NN) v = *(const us8*)&agg_bf[(size_t)n * 64 + q * 8];
        *(us8*)&xs[m * 136 + q * 8] = v;
    }
    // stage node feats (bf16), cols 64..127
    #pragma unroll
    for (int i = 0; i < 2; ++i) {
        int idx = t + 256 * i;
        int m = idx >> 3, q = idx & 7;
        int n = n0 + m;
        us8 v = {0, 0, 0, 0, 0, 0, 0, 0};
        if (n < NN) v = *(const us8*)&nodes_bf[(size_t)n * 64 + q * 8];
        *(us8*)&xs[m * 136 + 64 + q * 8] = v;
    }
    __syncthreads();

    // GEMM1: [64,128] @ Wn1[128,128], register weights
    f32x4 acc[4][2];
    #pragma unroll
    for (int mt = 0; mt < 4; ++mt) { acc[mt][0] = (f32x4)0.f; acc[mt][1] = (f32x4)0.f; }
    #pragma unroll
    for (int c = 0; c < 4; ++c) {
        #pragma unroll
        for (int mt = 0; mt < 4; ++mt) {
            bf16x8 a = *(const bf16x8*)&xs[(mt * 16 + lc) * 136 + c * 32 + lq * 8];
            acc[mt][0] = MFMA16(a, wA0[c], acc[mt][0], 0, 0, 0);
            acc[mt][1] = MFMA16(a, wA1[c], acc[mt][1], 0, 0, 0);
        }
    }
    __syncthreads();

    // bias + relu -> hs (same region, stride 136)
    #pragma unroll
    for (int nt = 0; nt < 2; ++nt) {
        int col = w * 32 + nt * 16 + lc;
        float bias = nt ? b1y : b1x;
        #pragma unroll
        for (int mt = 0; mt < 4; ++mt) {
            #pragma unroll
            for (int r = 0; r < 4; ++r) {
                int row = mt * 16 + lq * 4 + r;
                float v = fmaxf(acc[mt][nt][r] + bias, 0.f);
                xs[row * 136 + col] = f2b(v);
            }
        }
    }
    __syncthreads();

    // GEMM2: [64,128] @ Wn2[128,64], register weights
    f32x4 acc2[4];
    #pragma unroll
    for (int mt = 0; mt < 4; ++mt) acc2[mt] = (f32x4)0.f;
    #pragma unroll
    for (int c = 0; c < 4; ++c) {
        #pragma unroll
        for (int mt = 0; mt < 4; ++mt) {
            bf16x8 a = *(const bf16x8*)&xs[(mt * 16 + lc) * 136 + c * 32 + lq * 8];
            acc2[mt] = MFMA16(a, wB[c], acc2[mt], 0, 0, 0);
        }
    }

    const int col = w * 16 + lc;
    #pragma unroll
    for (int mt = 0; mt < 4; ++mt) {
        #pragma unroll
        for (int r = 0; r < 4; ++r) {
            int row = mt * 16 + lq * 4 + r;
            int n = n0 + row;
            if (n < NN) out[(size_t)n * 64 + col] = acc2[mt][r] + bias2;
        }
    }
}

extern "C" void kernel_launch(void* const* d_in, const int* in_sizes, int n_in,
                              void* d_out, int out_size, void* d_ws, size_t ws_size,
                              hipStream_t stream) {
    const float* nodes = (const float*)d_in[0];
    const float* edges = (const float*)d_in[1];
    const float* We1   = (const float*)d_in[2];
    const float* be1   = (const float*)d_in[3];
    const float* We2   = (const float*)d_in[4];
    const float* be2   = (const float*)d_in[5];
    const float* Wn1   = (const float*)d_in[6];
    const float* bn1   = (const float*)d_in[7];
    const float* Wn2   = (const float*)d_in[8];
    const float* bn2   = (const float*)d_in[9];
    const int* senders   = (const int*)d_in[10];
    const int* receivers = (const int*)d_in[11];
    float* out = (float*)d_out;

    // ws layout (bytes), total ~23.2 MB (harness provides >= 109 MB, verified round 3)
    char* ws = (char*)d_ws;
    unsigned short* agg_bf   = (unsigned short*)ws;               //  6,400,000
    unsigned short* nodes_bf = (unsigned short*)(ws +  6400000);  //  6,400,000
    unsigned short* We1T = (unsigned short*)(ws + 12800000);      //     49,152
    unsigned short* We2T = (unsigned short*)(ws + 12849152);      //     16,384
    unsigned short* Wn1T = (unsigned short*)(ws + 12865536);      //     32,768
    unsigned short* Wn2T = (unsigned short*)(ws + 12898304);      //     16,384
    int* perm    = (int*)(ws + 12914688);                         //  3,200,000
    int* rsorted = (int*)(ws + 16114688);                         //  3,200,000
    int* ssorted = (int*)(ws + 19314688);                         //  3,200,000
    int* deg     = (int*)(ws + 22514688);                         //    200,704 (NNP)
    int* basep   = (int*)(ws + 22715392);                         //    200,704 (NNP)
    int* cursor  = (int*)(ws + 22916096);                         //    200,000
    int* psum    = (int*)(ws + 23116096);                         //      1,024
    int* poff    = (int*)(ws + 23117120);                         //      1,024

    hipMemsetAsync(deg, 0, NNP * sizeof(int), stream);
    hipMemsetAsync(cursor, 0, NN * sizeof(int), stream);
    hipMemsetAsync(agg_bf, 0, (size_t)NN * 64 * sizeof(unsigned short), stream);
    prep_kernel<<<416, 256, 0, stream>>>(nodes, We1, We2, Wn1, Wn2,
                                         nodes_bf, We1T, We2T, Wn1T, Wn2T);
    hist_kernel<<<(NE + 255) / 256, 256, 0, stream>>>(receivers, deg);
    scan1_kernel<<<SCANB, 256, 0, stream>>>(deg, psum);
    scan2_kernel<<<1, 256, 0, stream>>>(psum, poff);
    scan3_kernel<<<SCANB, 256, 0, stream>>>(deg, poff, basep);
    perm_kernel<<<(NE + 255) / 256, 256, 0, stream>>>(receivers, senders, basep, cursor,
                                                      perm, rsorted, ssorted);
    edge_kernel<<<NE / 64, 256, 0, stream>>>(nodes_bf, edges, We1T, be1, We2T, be2,
                                             perm, rsorted, ssorted, basep, agg_bf);
    node_kernel<<<(NN + 63) / 64, 256, 0, stream>>>(nodes_bf, agg_bf, Wn1T, bn1, Wn2T, bn2, out);
}

// Round 6
// 435.827 us; speedup vs baseline: 1.1666x; 1.1350x over previous
//
#include <hip/hip_runtime.h>

#define NN 50000
#define NE 800000

typedef __attribute__((ext_vector_type(8))) short bf16x8;
typedef __attribute__((ext_vector_type(8))) unsigned short us8;
typedef __attribute__((ext_vector_type(4))) unsigned short us4;
typedef __attribute__((ext_vector_type(4))) float f32x4;

#define MFMA16 __builtin_amdgcn_mfma_f32_16x16x32_bf16

__device__ __forceinline__ unsigned short f2b(float f) {
    union { float f; unsigned int u; } x; x.f = f;
    unsigned int r = x.u + 0x7FFFu + ((x.u >> 16) & 1u);
    return (unsigned short)(r >> 16);
}

// packed bf16x2 atomic add (gfx950 native, memory-side RMW, fire-and-forget)
__device__ __forceinline__ void atomic_pk_add_bf16(unsigned short* addr, unsigned int pk) {
    asm volatile("global_atomic_pk_add_bf16 %0, %1, off" :: "v"(addr), "v"(pk) : "memory");
}

// ---------------- prep: convert nodes to bf16; convert+transpose weights ----------------
__global__ __launch_bounds__(256) void prep_kernel(
    const float* __restrict__ nodes,
    const float* __restrict__ We1, const float* __restrict__ We2,
    const float* __restrict__ Wn1, const float* __restrict__ Wn2,
    unsigned short* __restrict__ nodes_bf,
    unsigned short* __restrict__ We1T, unsigned short* __restrict__ We2T,
    unsigned short* __restrict__ Wn1T, unsigned short* __restrict__ Wn2T)
{
    const int b = blockIdx.x, t = threadIdx.x;
    if (b < 400) {
        const float4* src = (const float4*)nodes;
        for (int i = b * 256 + t; i < NN * 16; i += 400 * 256) {
            float4 v = src[i];
            us4 o; o[0] = f2b(v.x); o[1] = f2b(v.y); o[2] = f2b(v.z); o[3] = f2b(v.w);
            *(us4*)&nodes_bf[(size_t)i * 4] = o;
        }
    } else {
        const int base = (b - 400) * 256 + t;
        for (int idx = base; idx < 57344; idx += 16 * 256) {
            if (idx < 24576) {               // We1T[128][192] <- We1[192][128]
                int n = idx / 192, k = idx % 192;
                We1T[idx] = f2b(We1[k * 128 + n]);
            } else if (idx < 32768) {        // We2T[64][128] <- We2[128][64]
                int j = idx - 24576; int n = j / 128, k = j % 128;
                We2T[j] = f2b(We2[k * 64 + n]);
            } else if (idx < 49152) {        // Wn1T[128][128] <- Wn1[128][128]
                int j = idx - 32768; int n = j / 128, k = j % 128;
                Wn1T[j] = f2b(Wn1[k * 128 + n]);
            } else {                         // Wn2T[64][128] <- Wn2[128][64]
                int j = idx - 49152; int n = j / 128, k = j % 128;
                Wn2T[j] = f2b(Wn2[k * 64 + n]);
            }
        }
    }
}

// ---------------- edge kernel: 64 seq edges/block, reg weights, barrier-free tail ----------
// LDS: xs[64][200] bf16 input (hs aliases stride 136) + ridx/sidx = 26.1 KB -> 4 blocks/CU.
// (256,4): VGPR cap 128; live need ~112 (weights 64 + acc 32 + acc2 16) — no spill (R5-verified).
__global__ __launch_bounds__(256, 4) void edge_kernel(
    const unsigned short* __restrict__ nodes_bf, const float* __restrict__ edges,
    const unsigned short* __restrict__ We1T, const float* __restrict__ be1,
    const unsigned short* __restrict__ We2T, const float* __restrict__ be2,
    const int* __restrict__ senders, const int* __restrict__ receivers,
    unsigned short* __restrict__ agg_bf)
{
    __shared__ __align__(16) unsigned short xs[64 * 200];
    __shared__ int ridx[64];
    __shared__ int sidx[64];

    const int t = threadIdx.x;
    const int e0 = blockIdx.x * 64;
    const int w = t >> 6, l = t & 63, lc = l & 15, lq = l >> 4;

    if (t < 64) {
        ridx[t] = receivers[e0 + t];
        sidx[t] = senders[e0 + t];
    }

    // weights to registers (L2-hot after first wave of blocks): 16 frags
    bf16x8 wA0[6], wA1[6], wB[4];
    #pragma unroll
    for (int c = 0; c < 6; ++c) {
        wA0[c] = *(const bf16x8*)&We1T[(w * 32 + lc) * 192 + c * 32 + lq * 8];
        wA1[c] = *(const bf16x8*)&We1T[(w * 32 + 16 + lc) * 192 + c * 32 + lq * 8];
    }
    #pragma unroll
    for (int c = 0; c < 4; ++c)
        wB[c] = *(const bf16x8*)&We2T[(w * 16 + lc) * 128 + c * 32 + lq * 8];
    const float b1x = be1[w * 32 + lc];
    const float b1y = be1[w * 32 + 16 + lc];
    const float bias2 = be2[w * 16 + lc];

    __syncthreads();   // ridx/sidx visible

    // stage edges (fp32 -> bf16), sequential = coalesced streaming
    #pragma unroll
    for (int i = 0; i < 4; ++i) {
        int idx = t + 256 * i;
        int m = idx >> 4, q = idx & 15;
        float4 v = *(const float4*)&edges[((size_t)(e0 + m)) * 64 + q * 4];
        us4 o; o[0] = f2b(v.x); o[1] = f2b(v.y); o[2] = f2b(v.z); o[3] = f2b(v.w);
        *(us4*)&xs[m * 200 + q * 4] = o;
    }
    // gather receiver node feats
    #pragma unroll
    for (int i = 0; i < 2; ++i) {
        int idx = t + 256 * i;
        int m = idx >> 3, q = idx & 7;
        us8 v = *(const us8*)&nodes_bf[(size_t)ridx[m] * 64 + q * 8];
        *(us8*)&xs[m * 200 + 64 + q * 8] = v;
    }
    // gather sender node feats
    #pragma unroll
    for (int i = 0; i < 2; ++i) {
        int idx = t + 256 * i;
        int m = idx >> 3, q = idx & 7;
        us8 v = *(const us8*)&nodes_bf[(size_t)sidx[m] * 64 + q * 8];
        *(us8*)&xs[m * 200 + 128 + q * 8] = v;
    }
    __syncthreads();

    // GEMM1: [64,192] @ We1[192,128], register weights, no inner barriers
    f32x4 acc[4][2];
    #pragma unroll
    for (int mt = 0; mt < 4; ++mt) { acc[mt][0] = (f32x4)0.f; acc[mt][1] = (f32x4)0.f; }
    #pragma unroll
    for (int c = 0; c < 6; ++c) {
        #pragma unroll
        for (int mt = 0; mt < 4; ++mt) {
            bf16x8 a = *(const bf16x8*)&xs[(mt * 16 + lc) * 200 + c * 32 + lq * 8];
            acc[mt][0] = MFMA16(a, wA0[c], acc[mt][0], 0, 0, 0);
            acc[mt][1] = MFMA16(a, wA1[c], acc[mt][1], 0, 0, 0);
        }
    }
    __syncthreads();

    // bias + relu -> hs (aliases xs, stride 136)
    #pragma unroll
    for (int nt = 0; nt < 2; ++nt) {
        int col = w * 32 + nt * 16 + lc;
        float bias = nt ? b1y : b1x;
        #pragma unroll
        for (int mt = 0; mt < 4; ++mt) {
            #pragma unroll
            for (int r = 0; r < 4; ++r) {
                int row = mt * 16 + lq * 4 + r;
                float v = fmaxf(acc[mt][nt][r] + bias, 0.f);
                xs[row * 136 + col] = f2b(v);
            }
        }
    }
    __syncthreads();

    // GEMM2: [64,128] @ We2[128,64], register weights
    f32x4 acc2[4];
    #pragma unroll
    for (int mt = 0; mt < 4; ++mt) acc2[mt] = (f32x4)0.f;
    #pragma unroll
    for (int c = 0; c < 4; ++c) {
        #pragma unroll
        for (int mt = 0; mt < 4; ++mt) {
            bf16x8 a = *(const bf16x8*)&xs[(mt * 16 + lc) * 136 + c * 32 + lq * 8];
            acc2[mt] = MFMA16(a, wB[c], acc2[mt], 0, 0, 0);
        }
    }

    // ---- barrier-free tail: pair columns via shfl_xor(1), issue pk-bf16 atomics ----
    // lane holds C[row=mt*16+lq*4+r][col=w*16+lc]; partner lane (l^1) holds col^1.
    // even lanes issue pairs for mt 0,1; odd lanes for mt 2,3 -> each pair issued once.
    {
        const int colbase = w * 16 + (lc & ~1);
        const bool evenL = (lc & 1) == 0;
        #pragma unroll
        for (int mt = 0; mt < 4; ++mt) {
            #pragma unroll
            for (int r = 0; r < 4; ++r) {
                float v = acc2[mt][r] + bias2;
                float o = __shfl_xor(v, 1);
                if (evenL == (mt < 2)) {
                    unsigned int pk = evenL
                        ? ((unsigned int)f2b(v) | ((unsigned int)f2b(o) << 16))
                        : ((unsigned int)f2b(o) | ((unsigned int)f2b(v) << 16));
                    int row = mt * 16 + lq * 4 + r;
                    atomic_pk_add_bf16(&agg_bf[(size_t)ridx[row] * 64 + colbase], pk);
                }
            }
        }
    }
}

// ---------------- node kernel: 64 nodes/block, reg weights ----------------
__global__ __launch_bounds__(256, 4) void node_kernel(
    const unsigned short* __restrict__ nodes_bf, const unsigned short* __restrict__ agg_bf,
    const unsigned short* __restrict__ Wn1T, const float* __restrict__ bn1,
    const unsigned short* __restrict__ Wn2T, const float* __restrict__ bn2,
    float* __restrict__ out)
{
    __shared__ __align__(16) unsigned short xs[64 * 136];

    const int t = threadIdx.x;
    const int n0 = blockIdx.x * 64;
    const int w = t >> 6, l = t & 63, lc = l & 15, lq = l >> 4;

    // weights to registers: 12 frags
    bf16x8 wA0[4], wA1[4], wB[4];
    #pragma unroll
    for (int c = 0; c < 4; ++c) {
        wA0[c] = *(const bf16x8*)&Wn1T[(w * 32 + lc) * 128 + c * 32 + lq * 8];
        wA1[c] = *(const bf16x8*)&Wn1T[(w * 32 + 16 + lc) * 128 + c * 32 + lq * 8];
        wB[c]  = *(const bf16x8*)&Wn2T[(w * 16 + lc) * 128 + c * 32 + lq * 8];
    }
    const float b1x = bn1[w * 32 + lc];
    const float b1y = bn1[w * 32 + 16 + lc];
    const float bias2 = bn2[w * 16 + lc];

    // stage agg (bf16 copy), cols 0..63
    #pragma unroll
    for (int i = 0; i < 2; ++i) {
        int idx = t + 256 * i;
        int m = idx >> 3, q = idx & 7;
        int n = n0 + m;
        us8 v = {0, 0, 0, 0, 0, 0, 0, 0};
        if (n < NN) v = *(const us8*)&agg_bf[(size_t)n * 64 + q * 8];
        *(us8*)&xs[m * 136 + q * 8] = v;
    }
    // stage node feats (bf16), cols 64..127
    #pragma unroll
    for (int i = 0; i < 2; ++i) {
        int idx = t + 256 * i;
        int m = idx >> 3, q = idx & 7;
        int n = n0 + m;
        us8 v = {0, 0, 0, 0, 0, 0, 0, 0};
        if (n < NN) v = *(const us8*)&nodes_bf[(size_t)n * 64 + q * 8];
        *(us8*)&xs[m * 136 + 64 + q * 8] = v;
    }
    __syncthreads();

    // GEMM1: [64,128] @ Wn1[128,128], register weights
    f32x4 acc[4][2];
    #pragma unroll
    for (int mt = 0; mt < 4; ++mt) { acc[mt][0] = (f32x4)0.f; acc[mt][1] = (f32x4)0.f; }
    #pragma unroll
    for (int c = 0; c < 4; ++c) {
        #pragma unroll
        for (int mt = 0; mt < 4; ++mt) {
            bf16x8 a = *(const bf16x8*)&xs[(mt * 16 + lc) * 136 + c * 32 + lq * 8];
            acc[mt][0] = MFMA16(a, wA0[c], acc[mt][0], 0, 0, 0);
            acc[mt][1] = MFMA16(a, wA1[c], acc[mt][1], 0, 0, 0);
        }
    }
    __syncthreads();

    // bias + relu -> hs (same region, stride 136)
    #pragma unroll
    for (int nt = 0; nt < 2; ++nt) {
        int col = w * 32 + nt * 16 + lc;
        float bias = nt ? b1y : b1x;
        #pragma unroll
        for (int mt = 0; mt < 4; ++mt) {
            #pragma unroll
            for (int r = 0; r < 4; ++r) {
                int row = mt * 16 + lq * 4 + r;
                float v = fmaxf(acc[mt][nt][r] + bias, 0.f);
                xs[row * 136 + col] = f2b(v);
            }
        }
    }
    __syncthreads();

    // GEMM2: [64,128] @ Wn2[128,64], register weights
    f32x4 acc2[4];
    #pragma unroll
    for (int mt = 0; mt < 4; ++mt) acc2[mt] = (f32x4)0.f;
    #pragma unroll
    for (int c = 0; c < 4; ++c) {
        #pragma unroll
        for (int mt = 0; mt < 4; ++mt) {
            bf16x8 a = *(const bf16x8*)&xs[(mt * 16 + lc) * 136 + c * 32 + lq * 8];
            acc2[mt] = MFMA16(a, wB[c], acc2[mt], 0, 0, 0);
        }
    }

    const int col = w * 16 + lc;
    #pragma unroll
    for (int mt = 0; mt < 4; ++mt) {
        #pragma unroll
        for (int r = 0; r < 4; ++r) {
            int row = mt * 16 + lq * 4 + r;
            int n = n0 + row;
            if (n < NN) out[(size_t)n * 64 + col] = acc2[mt][r] + bias2;
        }
    }
}

extern "C" void kernel_launch(void* const* d_in, const int* in_sizes, int n_in,
                              void* d_out, int out_size, void* d_ws, size_t ws_size,
                              hipStream_t stream) {
    const float* nodes = (const float*)d_in[0];
    const float* edges = (const float*)d_in[1];
    const float* We1   = (const float*)d_in[2];
    const float* be1   = (const float*)d_in[3];
    const float* We2   = (const float*)d_in[4];
    const float* be2   = (const float*)d_in[5];
    const float* Wn1   = (const float*)d_in[6];
    const float* bn1   = (const float*)d_in[7];
    const float* Wn2   = (const float*)d_in[8];
    const float* bn2   = (const float*)d_in[9];
    const int* senders   = (const int*)d_in[10];
    const int* receivers = (const int*)d_in[11];
    float* out = (float*)d_out;

    // ws layout (bytes) — proven 19.3 MB layout
    char* ws = (char*)d_ws;
    unsigned short* agg_bf = (unsigned short*)ws;                //  6,400,000 B
    unsigned short* nodes_bf = (unsigned short*)(ws + 12800000); //  6,400,000 B
    unsigned short* We1T = (unsigned short*)(ws + 19200000);     //     49,152 B
    unsigned short* We2T = (unsigned short*)(ws + 19249152);     //     16,384 B
    unsigned short* Wn1T = (unsigned short*)(ws + 19265536);     //     32,768 B
    unsigned short* Wn2T = (unsigned short*)(ws + 19298304);     //     16,384 B

    hipMemsetAsync(agg_bf, 0, (size_t)NN * 64 * sizeof(unsigned short), stream);
    prep_kernel<<<416, 256, 0, stream>>>(nodes, We1, We2, Wn1, Wn2,
                                         nodes_bf, We1T, We2T, Wn1T, Wn2T);
    edge_kernel<<<NE / 64, 256, 0, stream>>>(nodes_bf, edges, We1T, be1, We2T, be2,
                                             senders, receivers, agg_bf);
    node_kernel<<<(NN + 63) / 64, 256, 0, stream>>>(nodes_bf, agg_bf, Wn1T, bn1, Wn2T, bn2, out);
}